// Round 1
// baseline (268.690 us; speedup 1.0000x reference)
//
#include <hip/hip_runtime.h>
#include <cstdint>

typedef unsigned int u32;
typedef unsigned long long u64;

#define N_BATCH 16
#define N_ROWS  25200
#define N_FEAT  85
#define N_CLS   80
#define MAX_NMS 1000
#define MAX_DET 300
#define KEY_INVALID 0xFF800000u   // key(-inf)

// ---- workspace layout (bytes) ----
#define WS_KEYS    0u                          // 16*25200*4 = 1,612,800
#define WS_CLS     1612800u                    // 16*25200*4
#define WS_SELBOX  3225600u                    // 16*1024*4*4 = 262,144
#define WS_SELOB   3487744u                    // 262,144
#define WS_SELAREA 3749888u                    // 16*1024*4 = 65,536
#define WS_SELSC   3815424u                    // 65,536
#define WS_SELCLS  3880960u                    // 65,536
#define WS_SELVAL  3946496u                    // 65,536
#define WS_GMASK   4012032u                    // 16*1000*16*8 = 2,048,000

__device__ __forceinline__ u32 score_key(float s) {
  u32 u = __float_as_uint(s);
  u32 o = (u & 0x80000000u) ? ~u : (u | 0x80000000u);
  return ~o;   // ascending key == descending score
}

// Stage A: per-row score/class. One thread per row.
__global__ __launch_bounds__(256) void k_score(const float* __restrict__ pred,
                                               u32* __restrict__ keys,
                                               u32* __restrict__ clsArr) {
  int r = blockIdx.x * 256 + threadIdx.x;
  if (r >= N_BATCH * N_ROWS) return;
  const float* p = pred + (size_t)r * N_FEAT;
  float obj = p[4];
  float best = -__builtin_inff();
  int bi = 0;
  #pragma unroll 8
  for (int j = 0; j < N_CLS; ++j) {
    float c = p[5 + j] * obj;            // exact reference product (argmax over products!)
    if (c > best) { best = c; bi = j; }  // strict > -> first occurrence, like jnp.argmax
  }
  bool valid = (obj > 0.3f) && (best > 0.3f);
  float s = valid ? best : -__builtin_inff();
  keys[r]   = score_key(s);
  clsArr[r] = (u32)bi;
}

// Stage B: per-batch exact top-1000 (desc score, asc index ties = jax.lax.top_k),
// then gather boxes/offset-boxes/areas for the selected rows.
__global__ __launch_bounds__(1024) void k_select(const float* __restrict__ pred,
    const u32* __restrict__ keys_g, const u32* __restrict__ cls_g,
    float* __restrict__ selBox, float* __restrict__ selOb, float* __restrict__ selArea,
    float* __restrict__ selScore, float* __restrict__ selCls, u32* __restrict__ selValid) {
  extern __shared__ char smem[];
  u32* keys = (u32*)smem;                 // [25200]            100800 B
  u32* hist = (u32*)(smem + 100800);      // [256]
  u32* wsum = (u32*)(smem + 101824);      // [16]
  u32* bc   = (u32*)(smem + 101888);      // [8] broadcast: 0=prefix 1=target 2=cnt
  u64* items= (u64*)(smem + 101920);      // [1024]             8192 B  (end 110112)

  const int b = blockIdx.x;
  const int t = threadIdx.x;
  const int lane = t & 63;
  const int wv = t >> 6;

  const u32* kg = keys_g + b * N_ROWS;
  for (int i = t; i < N_ROWS; i += 1024) keys[i] = kg[i];
  if (t == 0) { bc[0] = 0u; bc[1] = 999u; bc[2] = 0u; }
  __syncthreads();

  // ---- find T = key of rank 999 (0-indexed) via 4-level MSD radix ----
  for (int lev = 3; lev >= 0; --lev) {
    if (t < 256) hist[t] = 0u;
    __syncthreads();
    u32 prefix = bc[0];
    u32 maskhi = (lev == 3) ? 0u : (0xFFFFFFFFu << ((lev + 1) * 8));
    for (int i = t; i < N_ROWS; i += 1024) {
      u32 k = keys[i];
      if ((k & maskhi) == prefix) atomicAdd(&hist[(k >> (lev * 8)) & 255u], 1u);
    }
    __syncthreads();
    if (t == 0) {
      u32 target = bc[1]; u32 cum = 0; u32 d = 0;
      for (; d < 255u; ++d) { u32 c = hist[d]; if (cum + c > target) break; cum += c; }
      bc[0] = prefix | (d << (lev * 8));
      bc[1] = target - cum;
    }
    __syncthreads();
  }
  const u32 T = bc[0];

  // ---- collect: pass0 = keys<T (count<=999), pass1 = keys==T in index order ----
  for (int pass = 0; pass < 2; ++pass) {
    for (int base = 0; base < N_ROWS; base += 1024) {
      int i = base + t;
      u32 kv = 0; bool pr = false;
      if (i < N_ROWS) { kv = keys[i]; pr = (pass == 0) ? (kv < T) : (kv == T); }
      u64 ball = __ballot(pr);
      if (lane == 0) wsum[wv] = (u32)__popcll(ball);
      __syncthreads();
      u32 off = 0, tot = 0;
      for (int q = 0; q < 16; ++q) { u32 c = wsum[q]; if (q < wv) off += c; tot += c; }
      u32 pos = bc[2] + off + (u32)__popcll(ball & ((1ull << lane) - 1ull));
      if (pr && pos < (u32)MAX_NMS) items[pos] = ((u64)kv << 32) | (u32)i;
      __syncthreads();
      if (t == 0) bc[2] += tot;
      __syncthreads();
    }
  }
  if (t >= MAX_NMS) items[t] = ~0ull;   // pad slots 1000..1023 to sort-to-end

  // ---- bitonic sort 1024 u64 ascending: (key, idx) ----
  for (int k = 2; k <= 1024; k <<= 1) {
    for (int j = k >> 1; j > 0; j >>= 1) {
      __syncthreads();
      int ixj = t ^ j;
      if (ixj > t) {
        u64 a = items[t], bb = items[ixj];
        bool sw = ((t & k) == 0) ? (a > bb) : (a < bb);
        if (sw) { items[t] = bb; items[ixj] = a; }
      }
    }
  }
  __syncthreads();

  // ---- gather selected rows ----
  if (t < MAX_NMS) {
    u64 it = items[t];
    u32 key = (u32)(it >> 32);
    u32 row = (u32)(it & 0xFFFFFFFFu);
    u32 o = ~key;
    u32 sb = (o & 0x80000000u) ? (o ^ 0x80000000u) : ~o;   // invert score_key
    float score = __uint_as_float(sb);
    u32 valid = (key != KEY_INVALID) ? 1u : 0u;
    const float* p = pred + ((size_t)b * N_ROWS + row) * N_FEAT;
    float x = p[0], y = p[1], w = p[2], h = p[3];
    float x1 = x - w * 0.5f, y1 = y - h * 0.5f;
    float x2 = x + w * 0.5f, y2 = y + h * 0.5f;
    float cf = (float)cls_g[b * N_ROWS + row];
    float offv = cf * 4096.0f;                 // exact: int*2^12
    float o0 = x1 + offv, o1 = y1 + offv, o2 = x2 + offv, o3 = y2 + offv;
    float area = (o2 - o0) * (o3 - o1);        // area from OFFSET boxes, like reference
    int idx = b * 1024 + t;
    selBox[idx * 4 + 0] = x1; selBox[idx * 4 + 1] = y1;
    selBox[idx * 4 + 2] = x2; selBox[idx * 4 + 3] = y2;
    selOb [idx * 4 + 0] = o0; selOb [idx * 4 + 1] = o1;
    selOb [idx * 4 + 2] = o2; selOb [idx * 4 + 3] = o3;
    selArea[idx] = area;
    selScore[idx] = score;
    selCls[idx] = cf;
    selValid[idx] = valid;
  }
}

// Stage C: 1000x1000 IoU>thr bitmask. Grid (16 chunks, 16 batches).
__global__ __launch_bounds__(256) void k_mask(const float* __restrict__ selOb,
                                              const float* __restrict__ selArea,
                                              u64* __restrict__ gmask) {
  __shared__ float shob[MAX_NMS * 4];
  __shared__ float sharea[MAX_NMS];
  const int chunk = blockIdx.x;
  const int b = blockIdx.y;
  const int t = threadIdx.x;
  const float* ob = selOb + (size_t)b * 1024 * 4;
  const float* ar = selArea + (size_t)b * 1024;
  for (int i = t; i < MAX_NMS * 4; i += 256) shob[i] = ob[i];
  for (int i = t; i < MAX_NMS; i += 256) sharea[i] = ar[i];
  __syncthreads();
  for (int q = 0; q < 4; ++q) {
    int task = t + 256 * q;          // 1024 tasks: (ilocal, word)
    int il = task >> 4;
    int w  = task & 15;
    int i = chunk * 64 + il;
    if (i < MAX_NMS) {
      float a0 = shob[i*4+0], a1 = shob[i*4+1], a2 = shob[i*4+2], a3 = shob[i*4+3];
      float aa = sharea[i];
      u64 bits = 0;
      int jbase = w * 64;
      int jend = MAX_NMS - jbase; if (jend > 64) jend = 64;
      for (int jj = 0; jj < jend; ++jj) {
        int j = jbase + jj;
        float lt0 = fmaxf(a0, shob[j*4+0]);
        float lt1 = fmaxf(a1, shob[j*4+1]);
        float rb0 = fminf(a2, shob[j*4+2]);
        float rb1 = fminf(a3, shob[j*4+3]);
        float ww = fmaxf(rb0 - lt0, 0.0f);
        float hh = fmaxf(rb1 - lt1, 0.0f);
        float inter = ww * hh;
        float den = aa + sharea[j] - inter + 1e-7f;   // ((aa+aj)-inter)+eps, like ref
        float iou = inter / den;                       // IEEE f32 div, like ref
        bits |= ((u64)(iou > 0.45f)) << jj;
      }
      gmask[((size_t)b * MAX_NMS + i) * 16 + w] = bits;
    }
  }
}

// Stage D: greedy scan + output. One block per batch; wave 0 scans.
__global__ __launch_bounds__(256) void k_scan(const u64* __restrict__ gmask,
                                              const u32* __restrict__ selValid,
                                              const float* __restrict__ selBox,
                                              const float* __restrict__ selScore,
                                              const float* __restrict__ selCls,
                                              float* __restrict__ out) {
  extern __shared__ char smem[];
  u64* m = (u64*)smem;                         // [16000]  128000 B
  unsigned char* val = (unsigned char*)(smem + 128000);  // [1000]
  int* order = (int*)(smem + 129000);          // [300]
  u32* pcnt = (u32*)(smem + 130200);
  const int b = blockIdx.x;
  const int t = threadIdx.x;
  const u64* gm = gmask + (size_t)b * (MAX_NMS * 16);
  for (int i = t; i < MAX_NMS * 16; i += 256) m[i] = gm[i];
  for (int i = t; i < MAX_NMS; i += 256) val[i] = (unsigned char)selValid[b * 1024 + i];
  __syncthreads();

  if (t < 64) {
    u64 remv = 0; int cnt = 0;
    for (int i = 0; i < MAX_NMS && cnt < MAX_DET; ++i) {
      int w = i >> 6;
      u64 rw = __shfl(remv, w);                       // broadcast word holding bit i
      bool sup = (rw >> (i & 63)) & 1ull;
      bool ki = (val[i] != 0) && !sup;                // wave-uniform
      if (ki) {
        if (t < 16) remv |= m[i * 16 + t];
        if (t == 0) order[cnt] = i;
        ++cnt;
      }
    }
    if (t == 0) *pcnt = (u32)cnt;
  }
  __syncthreads();
  int cnt = (int)*pcnt;
  for (int s = t; s < MAX_DET; s += 256) {
    float o0=0,o1=0,o2=0,o3=0,o4=0,o5=0;
    if (s < cnt) {
      int i = order[s];
      int idx = b * 1024 + i;
      o0 = selBox[idx*4+0]; o1 = selBox[idx*4+1];
      o2 = selBox[idx*4+2]; o3 = selBox[idx*4+3];
      o4 = selScore[idx];   o5 = selCls[idx];
    }
    float* op = out + ((size_t)b * MAX_DET + s) * 6;
    op[0]=o0; op[1]=o1; op[2]=o2; op[3]=o3; op[4]=o4; op[5]=o5;
  }
}

extern "C" void kernel_launch(void* const* d_in, const int* in_sizes, int n_in,
                              void* d_out, int out_size, void* d_ws, size_t ws_size,
                              hipStream_t stream) {
  const float* pred = (const float*)d_in[0];
  float* out = (float*)d_out;
  char* ws = (char*)d_ws;
  u32* keys     = (u32*)(ws + WS_KEYS);
  u32* cls      = (u32*)(ws + WS_CLS);
  float* selBox = (float*)(ws + WS_SELBOX);
  float* selOb  = (float*)(ws + WS_SELOB);
  float* selArea= (float*)(ws + WS_SELAREA);
  float* selScore=(float*)(ws + WS_SELSC);
  float* selCls = (float*)(ws + WS_SELCLS);
  u32* selValid = (u32*)(ws + WS_SELVAL);
  u64* gmask    = (u64*)(ws + WS_GMASK);

  k_score<<<(N_BATCH * N_ROWS + 255) / 256, 256, 0, stream>>>(pred, keys, cls);
  k_select<<<N_BATCH, 1024, 110112, stream>>>(pred, keys, cls, selBox, selOb, selArea,
                                              selScore, selCls, selValid);
  k_mask<<<dim3(16, N_BATCH), 256, 0, stream>>>(selOb, selArea, gmask);
  k_scan<<<N_BATCH, 256, 130208, stream>>>(gmask, selValid, selBox, selScore, selCls, out);
}

// Round 2
// 220.034 us; speedup vs baseline: 1.2211x; 1.2211x over previous
//
#include <hip/hip_runtime.h>
#include <cstdint>

typedef unsigned int u32;
typedef unsigned long long u64;

#define N_BATCH 16
#define N_ROWS  25200
#define N_FEAT  85
#define N_CLS   80
#define MAX_NMS 1000
#define MAX_DET 300
#define KEY_INVALID 0xFF800000u   // key(-inf)

// ---- workspace layout (bytes) ----
#define WS_KEYS    0u                          // 16*25200*4 = 1,612,800
#define WS_CLS     1612800u                    // 16*25200*4
#define WS_SELBOX  3225600u                    // 16*1024*4*4 = 262,144
#define WS_SELOB   3487744u                    // 262,144
#define WS_SELAREA 3749888u                    // 16*1024*4 = 65,536
#define WS_SELSC   3815424u                    // 65,536
#define WS_SELCLS  3880960u                    // 65,536
#define WS_SELVAL  3946496u                    // 65,536
#define WS_GMASK   4012032u                    // 16*1000*16*8 = 2,048,000

__device__ __forceinline__ u32 score_key(float s) {
  u32 u = __float_as_uint(s);
  u32 o = (u & 0x80000000u) ? ~u : (u | 0x80000000u);
  return ~o;   // ascending key == descending score
}

// ---- Stage A: per-row score/class. LDS-staged coalesced loads. ----
// 128-thread block processes 128 rows: stage 128*85 floats via float4 (block
// base = blk*43520 B, 16B aligned), then thread t reads row t from LDS
// (stride 85 dwords, gcd(85,32)=1 -> bank-conflict-free).
#define SC_ROWS 128
__global__ __launch_bounds__(128) void k_score(const float* __restrict__ pred,
                                               u32* __restrict__ keys,
                                               u32* __restrict__ clsArr) {
  extern __shared__ char smem[];
  float* ld = (float*)smem;                       // 128*85 floats = 43520 B
  const int t = threadIdx.x;
  const int blk = blockIdx.x;
  const float4* src = (const float4*)(pred + (size_t)blk * (SC_ROWS * N_FEAT));
  float4* dst = (float4*)ld;
  const int n4 = SC_ROWS * N_FEAT / 4;            // 2720
  for (int i = t; i < n4; i += 128) dst[i] = src[i];
  __syncthreads();
  const float* row = ld + t * N_FEAT;
  float obj = row[4];
  float best = -__builtin_inff();
  int bi = 0;
  #pragma unroll 8
  for (int j = 0; j < N_CLS; ++j) {
    float c = row[5 + j] * obj;          // exact reference product
    if (c > best) { best = c; bi = j; }  // strict > -> first occurrence (jnp.argmax)
  }
  bool valid = (obj > 0.3f) && (best > 0.3f);
  float s = valid ? best : -__builtin_inff();
  int r = blk * SC_ROWS + t;
  keys[r]   = score_key(s);
  clsArr[r] = (u32)bi;
}

// ---- Stage B: per-batch exact top-1000 (desc score, asc index ties). ----
// Radix-select T (rank-999 key) with wave-aggregated atomics at the skewed
// top level; contiguous-range collect with one block scan; rank-sort the
// 1024 (key,idx) items and scatter gathers directly at position = rank.
__global__ __launch_bounds__(1024) void k_select(const float* __restrict__ pred,
    const u32* __restrict__ keys_g, const u32* __restrict__ cls_g,
    float* __restrict__ selBox, float* __restrict__ selOb, float* __restrict__ selArea,
    float* __restrict__ selScore, float* __restrict__ selCls, u32* __restrict__ selValid) {
  extern __shared__ char smem[];
  u32* keys = (u32*)smem;                 // [25200]  100800 B
  u32* hist = (u32*)(smem + 100800);      // [256]    -> 101824
  u32* wsum = (u32*)(smem + 101824);      // [32]     -> 101952
  u32* bc   = (u32*)(smem + 101952);      // [8]      -> 101984
  u64* items= (u64*)(smem + 101984);      // [1024]   -> 110176

  const int b = blockIdx.x;
  const int t = threadIdx.x;
  const int lane = t & 63;
  const int wv = t >> 6;

  const u32* kg = keys_g + b * N_ROWS;
  for (int i = t; i < N_ROWS; i += 1024) keys[i] = kg[i];
  items[t] = 0xFFFFFFFF00000000ull | (u32)t;   // distinct pads, sort last
  if (t == 0) { bc[0] = 0u; bc[1] = 999u; }
  __syncthreads();

  // ---- radix-select T = key of rank 999 ----
  for (int lev = 3; lev >= 0; --lev) {
    if (t < 256) hist[t] = 0u;
    __syncthreads();
    const u32 prefix = bc[0];
    const u32 target = bc[1];
    const u32 maskhi = (lev == 3) ? 0u : (0xFFFFFFFFu << ((lev + 1) * 8));
    const int sh = lev * 8;
    for (int base = 0; base < N_ROWS; base += 1024) {
      int i = base + t;
      bool pr = false; u32 bk = 0;
      if (i < N_ROWS) { u32 k = keys[i]; pr = ((k & maskhi) == prefix); bk = (k >> sh) & 255u; }
      if (lev == 3) {
        // wave-aggregated atomics: scores cluster into ~3 top-byte buckets
        u64 act = __ballot(pr);
        while (act) {
          int ldr = __ffsll((unsigned long long)act) - 1;
          u32 lb = __shfl(bk, ldr);
          u64 same = __ballot(pr && (bk == lb));
          if (lane == ldr) atomicAdd(&hist[lb], (u32)__popcll(same));
          act &= ~same;
        }
      } else {
        if (pr) atomicAdd(&hist[bk], 1u);   // low levels: spread across mantissa bits
      }
    }
    __syncthreads();
    // parallel digit scan: wave 0, 4 buckets/lane + shuffle prefix scan
    if (t < 64) {
      u32 c0 = hist[t*4], c1 = hist[t*4+1], c2 = hist[t*4+2], c3 = hist[t*4+3];
      u32 s4 = c0 + c1 + c2 + c3;
      u32 inc = s4;
      #pragma unroll
      for (int d = 1; d < 64; d <<= 1) { u32 o = __shfl_up(inc, d); if (lane >= d) inc += o; }
      u32 excl = inc - s4;
      u64 mb = __ballot(inc > target);
      int L = __ffsll((unsigned long long)mb) - 1;
      if (t == L) {
        u32 cum = excl; u32 d = (u32)t * 4u;
        if (cum + c0 <= target) { cum += c0; d++;
          if (cum + c1 <= target) { cum += c1; d++;
            if (cum + c2 <= target) { cum += c2; d++; } } }
        bc[0] = prefix | (d << sh);
        bc[1] = target - cum;
      }
    }
    __syncthreads();
  }
  const u32 T = bc[0];

  // ---- collect: contiguous per-thread ranges preserve index order ----
  const int RPT = 25;                      // 1024*25 >= 25200
  const int i0 = t * RPT;
  u32 c0 = 0, c1 = 0;
  for (int r = 0; r < RPT; ++r) {
    int i = i0 + r;
    if (i < N_ROWS) { u32 k = keys[i]; c0 += (k < T); c1 += (k == T); }
  }
  u32 packed = (c0 << 16) | c1;            // cum(c0)<=999, cum(c1)<=25200 -> no carry
  u32 inc = packed;
  #pragma unroll
  for (int d = 1; d < 64; d <<= 1) { u32 o = __shfl_up(inc, d); if (lane >= d) inc += o; }
  if (lane == 63) wsum[wv] = inc;
  __syncthreads();
  if (t < 16) {
    u32 v = wsum[t]; u32 iv = v;
    #pragma unroll
    for (int d = 1; d < 16; d <<= 1) { u32 o = __shfl_up(iv, d); if (lane >= d) iv += o; }
    wsum[t] = iv - v;                      // exclusive wave offsets
    if (t == 15) bc[2] = iv;               // packed block totals
  }
  __syncthreads();
  u32 excl = inc - packed + wsum[wv];
  u32 total0 = bc[2] >> 16;
  u32 p0 = excl >> 16;
  u32 p1 = total0 + (excl & 0xFFFFu);
  for (int r = 0; r < RPT; ++r) {
    int i = i0 + r;
    if (i < N_ROWS) {
      u32 k = keys[i];
      if (k < T)       { items[p0] = ((u64)k << 32) | (u32)i; p0++; }
      else if (k == T) { if (p1 < (u32)MAX_NMS) items[p1] = ((u64)k << 32) | (u32)i; p1++; }
    }
  }
  __syncthreads();

  // ---- rank-sort: rank = #items strictly smaller (key asc, idx asc) ----
  u64 mine = items[t];
  int rank = 0;
  for (int j = 0; j < 1024; ++j) rank += (items[j] < mine) ? 1 : 0;   // LDS broadcast

  // ---- gather + scatter at position = rank ----
  if (rank < MAX_NMS) {
    u32 key = (u32)(mine >> 32);
    u32 row = (u32)(mine & 0xFFFFFFFFu);
    u32 o = ~key;
    u32 sb = (o & 0x80000000u) ? (o ^ 0x80000000u) : ~o;   // invert score_key
    float score = __uint_as_float(sb);
    u32 valid = (key != KEY_INVALID) ? 1u : 0u;
    const float* p = pred + ((size_t)b * N_ROWS + row) * N_FEAT;
    float x = p[0], y = p[1], w = p[2], h = p[3];
    float x1 = x - w * 0.5f, y1 = y - h * 0.5f;
    float x2 = x + w * 0.5f, y2 = y + h * 0.5f;
    float cf = (float)cls_g[b * N_ROWS + row];
    float offv = cf * 4096.0f;
    float o0 = x1 + offv, o1 = y1 + offv, o2 = x2 + offv, o3 = y2 + offv;
    float area = (o2 - o0) * (o3 - o1);        // area from OFFSET boxes, like ref
    int idx = b * 1024 + rank;
    selBox[idx * 4 + 0] = x1; selBox[idx * 4 + 1] = y1;
    selBox[idx * 4 + 2] = x2; selBox[idx * 4 + 3] = y2;
    selOb [idx * 4 + 0] = o0; selOb [idx * 4 + 1] = o1;
    selOb [idx * 4 + 2] = o2; selOb [idx * 4 + 3] = o3;
    selArea[idx] = area;
    selScore[idx] = score;
    selCls[idx] = cf;
    selValid[idx] = valid;
  }
}

// ---- Stage C: 1000x1000 IoU>thr bitmask. Grid (16 chunks, 16 batches). ----
__global__ __launch_bounds__(256) void k_mask(const float* __restrict__ selOb,
                                              const float* __restrict__ selArea,
                                              u64* __restrict__ gmask) {
  __shared__ float shob[MAX_NMS * 4];
  __shared__ float sharea[MAX_NMS];
  const int chunk = blockIdx.x;
  const int b = blockIdx.y;
  const int t = threadIdx.x;
  const float* ob = selOb + (size_t)b * 1024 * 4;
  const float* ar = selArea + (size_t)b * 1024;
  for (int i = t; i < MAX_NMS * 4; i += 256) shob[i] = ob[i];
  for (int i = t; i < MAX_NMS; i += 256) sharea[i] = ar[i];
  __syncthreads();
  for (int q = 0; q < 4; ++q) {
    int task = t + 256 * q;          // 1024 tasks: (ilocal, word)
    int il = task >> 4;
    int w  = task & 15;
    int i = chunk * 64 + il;
    if (i < MAX_NMS) {
      float a0 = shob[i*4+0], a1 = shob[i*4+1], a2 = shob[i*4+2], a3 = shob[i*4+3];
      float aa = sharea[i];
      u64 bits = 0;
      int jbase = w * 64;
      int jend = MAX_NMS - jbase; if (jend > 64) jend = 64;
      for (int jj = 0; jj < jend; ++jj) {
        int j = jbase + jj;
        float lt0 = fmaxf(a0, shob[j*4+0]);
        float lt1 = fmaxf(a1, shob[j*4+1]);
        float rb0 = fminf(a2, shob[j*4+2]);
        float rb1 = fminf(a3, shob[j*4+3]);
        float ww = fmaxf(rb0 - lt0, 0.0f);
        float hh = fmaxf(rb1 - lt1, 0.0f);
        float inter = ww * hh;
        float den = aa + sharea[j] - inter + 1e-7f;   // ((aa+aj)-inter)+eps, like ref
        float iou = inter / den;                       // IEEE f32 div, like ref
        bits |= ((u64)(iou > 0.45f)) << jj;
      }
      gmask[((size_t)b * MAX_NMS + i) * 16 + w] = bits;
    }
  }
}

// ---- Stage D: greedy scan + output. One block per batch; wave 0 scans. ----
__global__ __launch_bounds__(256) void k_scan(const u64* __restrict__ gmask,
                                              const u32* __restrict__ selValid,
                                              const float* __restrict__ selBox,
                                              const float* __restrict__ selScore,
                                              const float* __restrict__ selCls,
                                              float* __restrict__ out) {
  extern __shared__ char smem[];
  u64* m = (u64*)smem;                         // [16000]  128000 B
  unsigned char* val = (unsigned char*)(smem + 128000);  // [1000]
  int* order = (int*)(smem + 129000);          // [300]
  u32* pcnt = (u32*)(smem + 130200);
  const int b = blockIdx.x;
  const int t = threadIdx.x;
  const u64* gm = gmask + (size_t)b * (MAX_NMS * 16);
  for (int i = t; i < MAX_NMS * 16; i += 256) m[i] = gm[i];
  for (int i = t; i < MAX_NMS; i += 256) val[i] = (unsigned char)selValid[b * 1024 + i];
  __syncthreads();

  if (t < 64) {
    u64 remv = 0; int cnt = 0;
    for (int i = 0; i < MAX_NMS && cnt < MAX_DET; ++i) {
      int w = i >> 6;
      u64 rw = __shfl(remv, w);                       // broadcast word holding bit i
      bool sup = (rw >> (i & 63)) & 1ull;
      bool ki = (val[i] != 0) && !sup;                // wave-uniform
      if (ki) {
        if (t < 16) remv |= m[i * 16 + t];
        if (t == 0) order[cnt] = i;
        ++cnt;
      }
    }
    if (t == 0) *pcnt = (u32)cnt;
  }
  __syncthreads();
  int cnt = (int)*pcnt;
  for (int s = t; s < MAX_DET; s += 256) {
    float o0=0,o1=0,o2=0,o3=0,o4=0,o5=0;
    if (s < cnt) {
      int i = order[s];
      int idx = b * 1024 + i;
      o0 = selBox[idx*4+0]; o1 = selBox[idx*4+1];
      o2 = selBox[idx*4+2]; o3 = selBox[idx*4+3];
      o4 = selScore[idx];   o5 = selCls[idx];
    }
    float* op = out + ((size_t)b * MAX_DET + s) * 6;
    op[0]=o0; op[1]=o1; op[2]=o2; op[3]=o3; op[4]=o4; op[5]=o5;
  }
}

extern "C" void kernel_launch(void* const* d_in, const int* in_sizes, int n_in,
                              void* d_out, int out_size, void* d_ws, size_t ws_size,
                              hipStream_t stream) {
  const float* pred = (const float*)d_in[0];
  float* out = (float*)d_out;
  char* ws = (char*)d_ws;
  u32* keys     = (u32*)(ws + WS_KEYS);
  u32* cls      = (u32*)(ws + WS_CLS);
  float* selBox = (float*)(ws + WS_SELBOX);
  float* selOb  = (float*)(ws + WS_SELOB);
  float* selArea= (float*)(ws + WS_SELAREA);
  float* selScore=(float*)(ws + WS_SELSC);
  float* selCls = (float*)(ws + WS_SELCLS);
  u32* selValid = (u32*)(ws + WS_SELVAL);
  u64* gmask    = (u64*)(ws + WS_GMASK);

  k_score<<<(N_BATCH * N_ROWS) / SC_ROWS, SC_ROWS, SC_ROWS * N_FEAT * 4, stream>>>(pred, keys, cls);
  k_select<<<N_BATCH, 1024, 110176, stream>>>(pred, keys, cls, selBox, selOb, selArea,
                                              selScore, selCls, selValid);
  k_mask<<<dim3(16, N_BATCH), 256, 0, stream>>>(selOb, selArea, gmask);
  k_scan<<<N_BATCH, 256, 130208, stream>>>(gmask, selValid, selBox, selScore, selCls, out);
}

// Round 3
// 199.604 us; speedup vs baseline: 1.3461x; 1.1024x over previous
//
#include <hip/hip_runtime.h>
#include <cstdint>

typedef unsigned int u32;
typedef unsigned long long u64;

#define N_BATCH 16
#define N_ROWS  25200
#define N_FEAT  85
#define N_CLS   80
#define MAX_NMS 1000
#define MAX_DET 300
#define KEY_INVALID 0xFF800000u   // key(-inf)

// ---- workspace layout (bytes) ----
#define WS_KEYS    0u                          // 16*25200*4 = 1,612,800
#define WS_CLS     1612800u                    // 16*25200*4
#define WS_SELBOX  3225600u                    // 16*1024*4*4 = 262,144
#define WS_SELOB   3487744u                    // 262,144
#define WS_SELAREA 3749888u                    // 16*1024*4 = 65,536
#define WS_SELSC   3815424u                    // 65,536
#define WS_SELCLS  3880960u                    // 65,536
#define WS_SELVAL  3946496u                    // 65,536
#define WS_GMASK   4012032u                    // 16*1000*16*8 = 2,048,000

__device__ __forceinline__ u32 score_key(float s) {
  u32 u = __float_as_uint(s);
  u32 o = (u & 0x80000000u) ? ~u : (u | 0x80000000u);
  return ~o;   // ascending key == descending score
}

// ---- Stage A: per-row score/class. Wave-synchronous, no barriers. ----
// Each wave stages a 16-row chunk (340 float4 = 5440 B, 16B-aligned since
// 16*85*4 % 16 == 0) into its private LDS slice via coalesced float4, then
// 4 lanes/row (20 classes each) reduce (max, first-index) via shfl_xor.
// 21.76 KB LDS / 256-thread block -> 7 blocks/CU -> 28 waves/CU: TLP hides
// HBM latency without any double-buffering.
#define SC_CHUNK 16
#define SC_GRID  1792   // 7 blocks/CU * 256 CU
__global__ __launch_bounds__(256) void k_score(const float* __restrict__ pred,
                                               u32* __restrict__ keys,
                                               u32* __restrict__ clsArr) {
  __shared__ float ld[4][SC_CHUNK * N_FEAT];    // 4 waves * 1360 floats = 21760 B
  const int t = threadIdx.x;
  const int lane = t & 63;
  const int wv = t >> 6;
  float* buf = ld[wv];
  const int row = lane & 15;
  const int q = lane >> 4;                      // class quarter: j in [20q, 20q+20)
  const int gw = blockIdx.x * 4 + wv;
  const int nw = SC_GRID * 4;
  const int nchunks = (N_BATCH * N_ROWS) / SC_CHUNK;   // 25200

  for (int c = gw; c < nchunks; c += nw) {
    const float4* src = (const float4*)(pred + (size_t)c * (SC_CHUNK * N_FEAT));
    float4* dst = (float4*)buf;
    #pragma unroll
    for (int qq = 0; qq < 5; ++qq) dst[lane + 64 * qq] = src[lane + 64 * qq];
    if (lane < 20) dst[lane + 320] = src[lane + 320];
    // same-wave RAW through LDS: compiler inserts vmcnt/lgkmcnt waits; LDS ops
    // per wave are in-order so next iteration's writes can't pass these reads.
    float obj = buf[row * N_FEAT + 4];
    float best = -__builtin_inff();
    int bi = 0;
    const float* cp = buf + row * N_FEAT + 5 + q * 20;
    #pragma unroll
    for (int j = 0; j < 20; ++j) {
      float cc = cp[j] * obj;                  // exact reference product
      if (cc > best) { best = cc; bi = q * 20 + j; }   // strict > = first occurrence
    }
    // combine the 4 quarter-lanes: lexicographic (score desc, index asc)
    #pragma unroll
    for (int d = 16; d <= 32; d <<= 1) {
      float ob = __shfl_xor(best, d);
      int oj = __shfl_xor(bi, d);
      if (ob > best || (ob == best && oj < bi)) { best = ob; bi = oj; }
    }
    if (q == 0) {
      bool valid = (obj > 0.3f) && (best > 0.3f);
      float s = valid ? best : -__builtin_inff();
      int gr = c * SC_CHUNK + row;
      keys[gr] = score_key(s);
      clsArr[gr] = (u32)bi;
    }
  }
}

// ---- Stage B: per-batch exact top-1000 (desc score, asc index ties). ----
__global__ __launch_bounds__(1024) void k_select(const float* __restrict__ pred,
    const u32* __restrict__ keys_g, const u32* __restrict__ cls_g,
    float* __restrict__ selBox, float* __restrict__ selOb, float* __restrict__ selArea,
    float* __restrict__ selScore, float* __restrict__ selCls, u32* __restrict__ selValid) {
  extern __shared__ char smem[];
  u32* keys = (u32*)smem;                 // [25200]  100800 B
  u32* hist = (u32*)(smem + 100800);      // [256]    -> 101824
  u32* wsum = (u32*)(smem + 101824);      // [32]     -> 101952
  u32* bc   = (u32*)(smem + 101952);      // [8]      -> 101984
  u64* items= (u64*)(smem + 101984);      // [1024]   -> 110176

  const int b = blockIdx.x;
  const int t = threadIdx.x;
  const int lane = t & 63;
  const int wv = t >> 6;

  const u32* kg = keys_g + b * N_ROWS;
  for (int i = t; i < N_ROWS; i += 1024) keys[i] = kg[i];
  items[t] = 0xFFFFFFFF00000000ull | (u32)t;   // distinct pads, sort last
  if (t == 0) { bc[0] = 0u; bc[1] = 999u; }
  __syncthreads();

  // ---- radix-select T = key of rank 999 ----
  for (int lev = 3; lev >= 0; --lev) {
    if (t < 256) hist[t] = 0u;
    __syncthreads();
    const u32 prefix = bc[0];
    const u32 target = bc[1];
    const u32 maskhi = (lev == 3) ? 0u : (0xFFFFFFFFu << ((lev + 1) * 8));
    const int sh = lev * 8;
    for (int base = 0; base < N_ROWS; base += 1024) {
      int i = base + t;
      bool pr = false; u32 bk = 0;
      if (i < N_ROWS) { u32 k = keys[i]; pr = ((k & maskhi) == prefix); bk = (k >> sh) & 255u; }
      if (lev == 3) {
        // wave-aggregated atomics: scores cluster into ~3 top-byte buckets
        u64 act = __ballot(pr);
        while (act) {
          int ldr = __ffsll((unsigned long long)act) - 1;
          u32 lb = __shfl(bk, ldr);
          u64 same = __ballot(pr && (bk == lb));
          if (lane == ldr) atomicAdd(&hist[lb], (u32)__popcll(same));
          act &= ~same;
        }
      } else {
        if (pr) atomicAdd(&hist[bk], 1u);   // low levels: spread across mantissa bits
      }
    }
    __syncthreads();
    // parallel digit scan: wave 0, 4 buckets/lane + shuffle prefix scan
    if (t < 64) {
      u32 c0 = hist[t*4], c1 = hist[t*4+1], c2 = hist[t*4+2], c3 = hist[t*4+3];
      u32 s4 = c0 + c1 + c2 + c3;
      u32 inc = s4;
      #pragma unroll
      for (int d = 1; d < 64; d <<= 1) { u32 o = __shfl_up(inc, d); if (lane >= d) inc += o; }
      u32 excl = inc - s4;
      u64 mb = __ballot(inc > target);
      int L = __ffsll((unsigned long long)mb) - 1;
      if (t == L) {
        u32 cum = excl; u32 d = (u32)t * 4u;
        if (cum + c0 <= target) { cum += c0; d++;
          if (cum + c1 <= target) { cum += c1; d++;
            if (cum + c2 <= target) { cum += c2; d++; } } }
        bc[0] = prefix | (d << sh);
        bc[1] = target - cum;
      }
    }
    __syncthreads();
  }
  const u32 T = bc[0];

  // ---- collect: contiguous per-thread ranges preserve index order ----
  const int RPT = 25;                      // 1024*25 >= 25200
  const int i0 = t * RPT;
  u32 c0 = 0, c1 = 0;
  for (int r = 0; r < RPT; ++r) {
    int i = i0 + r;
    if (i < N_ROWS) { u32 k = keys[i]; c0 += (k < T); c1 += (k == T); }
  }
  u32 packed = (c0 << 16) | c1;            // cum(c0)<=999, cum(c1)<=25200 -> no carry
  u32 inc = packed;
  #pragma unroll
  for (int d = 1; d < 64; d <<= 1) { u32 o = __shfl_up(inc, d); if (lane >= d) inc += o; }
  if (lane == 63) wsum[wv] = inc;
  __syncthreads();
  if (t < 16) {
    u32 v = wsum[t]; u32 iv = v;
    #pragma unroll
    for (int d = 1; d < 16; d <<= 1) { u32 o = __shfl_up(iv, d); if (lane >= d) iv += o; }
    wsum[t] = iv - v;                      // exclusive wave offsets
    if (t == 15) bc[2] = iv;               // packed block totals
  }
  __syncthreads();
  u32 excl = inc - packed + wsum[wv];
  u32 total0 = bc[2] >> 16;
  u32 p0 = excl >> 16;
  u32 p1 = total0 + (excl & 0xFFFFu);
  for (int r = 0; r < RPT; ++r) {
    int i = i0 + r;
    if (i < N_ROWS) {
      u32 k = keys[i];
      if (k < T)       { items[p0] = ((u64)k << 32) | (u32)i; p0++; }
      else if (k == T) { if (p1 < (u32)MAX_NMS) items[p1] = ((u64)k << 32) | (u32)i; p1++; }
    }
  }
  __syncthreads();

  // ---- rank-sort: rank = #items strictly smaller (key asc, idx asc) ----
  u64 mine = items[t];
  int rank = 0;
  for (int j = 0; j < 1024; ++j) rank += (items[j] < mine) ? 1 : 0;   // LDS broadcast

  // ---- gather + scatter at position = rank ----
  if (rank < MAX_NMS) {
    u32 key = (u32)(mine >> 32);
    u32 row = (u32)(mine & 0xFFFFFFFFu);
    u32 o = ~key;
    u32 sb = (o & 0x80000000u) ? (o ^ 0x80000000u) : ~o;   // invert score_key
    float score = __uint_as_float(sb);
    u32 valid = (key != KEY_INVALID) ? 1u : 0u;
    const float* p = pred + ((size_t)b * N_ROWS + row) * N_FEAT;
    float x = p[0], y = p[1], w = p[2], h = p[3];
    float x1 = x - w * 0.5f, y1 = y - h * 0.5f;
    float x2 = x + w * 0.5f, y2 = y + h * 0.5f;
    float cf = (float)cls_g[b * N_ROWS + row];
    float offv = cf * 4096.0f;
    float o0 = x1 + offv, o1 = y1 + offv, o2 = x2 + offv, o3 = y2 + offv;
    float area = (o2 - o0) * (o3 - o1);        // area from OFFSET boxes, like ref
    int idx = b * 1024 + rank;
    selBox[idx * 4 + 0] = x1; selBox[idx * 4 + 1] = y1;
    selBox[idx * 4 + 2] = x2; selBox[idx * 4 + 3] = y2;
    selOb [idx * 4 + 0] = o0; selOb [idx * 4 + 1] = o1;
    selOb [idx * 4 + 2] = o2; selOb [idx * 4 + 3] = o3;
    selArea[idx] = area;
    selScore[idx] = score;
    selCls[idx] = cf;
    selValid[idx] = valid;
  }
}

// ---- Stage C: 1000x1000 IoU>thr bitmask. Grid (16 chunks, 16 batches). ----
__global__ __launch_bounds__(256) void k_mask(const float* __restrict__ selOb,
                                              const float* __restrict__ selArea,
                                              u64* __restrict__ gmask) {
  __shared__ float shob[MAX_NMS * 4];
  __shared__ float sharea[MAX_NMS];
  const int chunk = blockIdx.x;
  const int b = blockIdx.y;
  const int t = threadIdx.x;
  const float* ob = selOb + (size_t)b * 1024 * 4;
  const float* ar = selArea + (size_t)b * 1024;
  for (int i = t; i < MAX_NMS * 4; i += 256) shob[i] = ob[i];
  for (int i = t; i < MAX_NMS; i += 256) sharea[i] = ar[i];
  __syncthreads();
  for (int q = 0; q < 4; ++q) {
    int task = t + 256 * q;          // 1024 tasks: (ilocal, word)
    int il = task >> 4;
    int w  = task & 15;
    int i = chunk * 64 + il;
    if (i < MAX_NMS) {
      float a0 = shob[i*4+0], a1 = shob[i*4+1], a2 = shob[i*4+2], a3 = shob[i*4+3];
      float aa = sharea[i];
      u64 bits = 0;
      int jbase = w * 64;
      int jend = MAX_NMS - jbase; if (jend > 64) jend = 64;
      for (int jj = 0; jj < jend; ++jj) {
        int j = jbase + jj;
        float lt0 = fmaxf(a0, shob[j*4+0]);
        float lt1 = fmaxf(a1, shob[j*4+1]);
        float rb0 = fminf(a2, shob[j*4+2]);
        float rb1 = fminf(a3, shob[j*4+3]);
        float ww = fmaxf(rb0 - lt0, 0.0f);
        float hh = fmaxf(rb1 - lt1, 0.0f);
        float inter = ww * hh;
        float den = aa + sharea[j] - inter + 1e-7f;   // ((aa+aj)-inter)+eps, like ref
        float iou = inter / den;                       // IEEE f32 div, like ref
        bits |= ((u64)(iou > 0.45f)) << jj;
      }
      gmask[((size_t)b * MAX_NMS + i) * 16 + w] = bits;
    }
  }
}

// ---- Stage D: greedy scan + output. One block per batch; wave 0 scans. ----
__global__ __launch_bounds__(256) void k_scan(const u64* __restrict__ gmask,
                                              const u32* __restrict__ selValid,
                                              const float* __restrict__ selBox,
                                              const float* __restrict__ selScore,
                                              const float* __restrict__ selCls,
                                              float* __restrict__ out) {
  extern __shared__ char smem[];
  u64* m = (u64*)smem;                         // [16000]  128000 B
  unsigned char* val = (unsigned char*)(smem + 128000);  // [1000]
  int* order = (int*)(smem + 129000);          // [300]
  u32* pcnt = (u32*)(smem + 130200);
  const int b = blockIdx.x;
  const int t = threadIdx.x;
  const u64* gm = gmask + (size_t)b * (MAX_NMS * 16);
  for (int i = t; i < MAX_NMS * 16; i += 256) m[i] = gm[i];
  for (int i = t; i < MAX_NMS; i += 256) val[i] = (unsigned char)selValid[b * 1024 + i];
  __syncthreads();

  if (t < 64) {
    u64 remv = 0; int cnt = 0;
    for (int i = 0; i < MAX_NMS && cnt < MAX_DET; ++i) {
      int w = i >> 6;
      u64 rw = __shfl(remv, w);                       // broadcast word holding bit i
      bool sup = (rw >> (i & 63)) & 1ull;
      bool ki = (val[i] != 0) && !sup;                // wave-uniform
      if (ki) {
        if (t < 16) remv |= m[i * 16 + t];
        if (t == 0) order[cnt] = i;
        ++cnt;
      }
    }
    if (t == 0) *pcnt = (u32)cnt;
  }
  __syncthreads();
  int cnt = (int)*pcnt;
  for (int s = t; s < MAX_DET; s += 256) {
    float o0=0,o1=0,o2=0,o3=0,o4=0,o5=0;
    if (s < cnt) {
      int i = order[s];
      int idx = b * 1024 + i;
      o0 = selBox[idx*4+0]; o1 = selBox[idx*4+1];
      o2 = selBox[idx*4+2]; o3 = selBox[idx*4+3];
      o4 = selScore[idx];   o5 = selCls[idx];
    }
    float* op = out + ((size_t)b * MAX_DET + s) * 6;
    op[0]=o0; op[1]=o1; op[2]=o2; op[3]=o3; op[4]=o4; op[5]=o5;
  }
}

extern "C" void kernel_launch(void* const* d_in, const int* in_sizes, int n_in,
                              void* d_out, int out_size, void* d_ws, size_t ws_size,
                              hipStream_t stream) {
  const float* pred = (const float*)d_in[0];
  float* out = (float*)d_out;
  char* ws = (char*)d_ws;
  u32* keys     = (u32*)(ws + WS_KEYS);
  u32* cls      = (u32*)(ws + WS_CLS);
  float* selBox = (float*)(ws + WS_SELBOX);
  float* selOb  = (float*)(ws + WS_SELOB);
  float* selArea= (float*)(ws + WS_SELAREA);
  float* selScore=(float*)(ws + WS_SELSC);
  float* selCls = (float*)(ws + WS_SELCLS);
  u32* selValid = (u32*)(ws + WS_SELVAL);
  u64* gmask    = (u64*)(ws + WS_GMASK);

  k_score<<<SC_GRID, 256, 0, stream>>>(pred, keys, cls);
  k_select<<<N_BATCH, 1024, 110176, stream>>>(pred, keys, cls, selBox, selOb, selArea,
                                              selScore, selCls, selValid);
  k_mask<<<dim3(16, N_BATCH), 256, 0, stream>>>(selOb, selArea, gmask);
  k_scan<<<N_BATCH, 256, 130208, stream>>>(gmask, selValid, selBox, selScore, selCls, out);
}

// Round 4
// 165.870 us; speedup vs baseline: 1.6199x; 1.2034x over previous
//
#include <hip/hip_runtime.h>
#include <cstdint>

typedef unsigned int u32;
typedef unsigned long long u64;

#define N_BATCH 16
#define N_ROWS  25200
#define N_FEAT  85
#define N_CLS   80
#define MAX_NMS 1000
#define MAX_DET 300
#define KEY_INVALID 0xFF800000u   // key(-inf)

// ---- workspace layout (bytes) ----
#define WS_KEYS    0u                          // 16*25200*4 = 1,612,800
#define WS_CLS     1612800u                    // 16*25200*4
#define WS_SELBOX  3225600u                    // 16*1024*4*4 = 262,144
#define WS_SELOB   3487744u                    // 262,144
#define WS_SELAREA 3749888u                    // 16*1024*4 = 65,536
#define WS_SELSC   3815424u                    // 65,536
#define WS_SELCLS  3880960u                    // 65,536
#define WS_SELVAL  3946496u                    // 65,536
#define WS_GMASK   4012032u                    // 16*1000*16*8 = 2,048,000

__device__ __forceinline__ u32 score_key(float s) {
  u32 u = __float_as_uint(s);
  u32 o = (u & 0x80000000u) ? ~u : (u | 0x80000000u);
  return ~o;   // ascending key == descending score
}

// ---- Stage A: per-row score/class, async-pipelined LDS staging. ----
// Chunk = 32 rows = 10880 B. Two LDS buffers (21.76 KB total -> 7 blocks/CU).
// Staging via global_load_lds width=16 (no VGPR roundtrip): each wave covers
// 170 16B-units (3 issues: 64+64+42 lanes). Prefetch distance 2 with counted
// vmcnt (never 0 in steady state) + raw s_barrier so loads span barriers.
#define KS_CHUNK  32
#define KS_CBYTES (KS_CHUNK * N_FEAT * 4)     // 10880
#define KS_GRID   1792                        // 7 blocks/CU * 256 CU
#define KS_NCHUNK ((N_BATCH * N_ROWS) / KS_CHUNK)   // 12600

__device__ __forceinline__ void ks_stage(const float* pred, int c, u32* lbuf,
                                         int wv, int lane) {
  const char* g = (const char*)pred + (size_t)c * KS_CBYTES;
  const int u0 = wv * 170;
  u32* l0 = lbuf + u0 * 4;
  __builtin_amdgcn_global_load_lds(
      (const __attribute__((address_space(1))) u32*)(g + (size_t)(u0 + lane) * 16),
      (__attribute__((address_space(3))) u32*)(l0), 16, 0, 0);
  __builtin_amdgcn_global_load_lds(
      (const __attribute__((address_space(1))) u32*)(g + (size_t)(u0 + 64 + lane) * 16),
      (__attribute__((address_space(3))) u32*)(l0 + 256), 16, 0, 0);
  if (lane < 42)
    __builtin_amdgcn_global_load_lds(
        (const __attribute__((address_space(1))) u32*)(g + (size_t)(u0 + 128 + lane) * 16),
        (__attribute__((address_space(3))) u32*)(l0 + 512), 16, 0, 0);
}

__global__ __launch_bounds__(256) void k_score(const float* __restrict__ pred,
                                               u32* __restrict__ keys,
                                               u32* __restrict__ clsArr) {
  __shared__ __align__(16) u32 sbuf[2][KS_CBYTES / 4];
  const int t = threadIdx.x;
  const int lane = t & 63;
  const int wv = t >> 6;
  const int row = (lane >> 3) + wv * 8;     // 0..31 within chunk
  const int sub = lane & 7;                 // class slice [10*sub, 10*sub+10)

  // prologue: stage chunks c0, c0+GRID (every block has >=7 chunks)
  ks_stage(pred, blockIdx.x, sbuf[0], wv, lane);
  ks_stage(pred, blockIdx.x + KS_GRID, sbuf[1], wv, lane);

  int it = 0;
  for (int c = blockIdx.x; c < KS_NCHUNK; c += KS_GRID, ++it) {
    const bool has_next = (c + KS_GRID < KS_NCHUNK);
    // wait current buffer's 3 loads (oldest); keep prefetch in flight
    if (it == 0)        asm volatile("s_waitcnt vmcnt(3)" ::: "memory");
    else if (has_next)  asm volatile("s_waitcnt vmcnt(5)" ::: "memory");
    else                asm volatile("s_waitcnt vmcnt(2)" ::: "memory");
    __builtin_amdgcn_sched_barrier(0);
    __builtin_amdgcn_s_barrier();          // all waves' loads for cur landed

    const u32* rp = sbuf[it & 1] + row * N_FEAT;
    float obj = __uint_as_float(rp[4]);
    float best = -__builtin_inff();
    int bi = 0;
    const u32* cp = rp + 5 + sub * 10;
    #pragma unroll
    for (int k = 0; k < 10; ++k) {
      float cc = __uint_as_float(cp[k]) * obj;     // exact reference product
      if (cc > best) { best = cc; bi = sub * 10 + k; } // strict > = first occ.
    }
    #pragma unroll
    for (int d = 1; d <= 4; d <<= 1) {     // merge 8 sub-lanes, lexicographic
      float ob = __shfl_xor(best, d);
      int oj = __shfl_xor(bi, d);
      if (ob > best || (ob == best && oj < bi)) { best = ob; bi = oj; }
    }
    if (sub == 0) {
      bool valid = (obj > 0.3f) && (best > 0.3f);
      float s = valid ? best : -__builtin_inff();
      int gr = c * KS_CHUNK + row;
      keys[gr] = score_key(s);
      clsArr[gr] = (u32)bi;
    }
    __builtin_amdgcn_s_barrier();          // all waves done reading cur
    if (c + 2 * KS_GRID < KS_NCHUNK)
      ks_stage(pred, c + 2 * KS_GRID, sbuf[it & 1], wv, lane);
  }
}

// ---- Stage B: per-batch exact top-1000 (desc score, asc index ties). ----
// Radix-select T (rank-999 key, aggregated atomics at the skewed top level),
// contiguous-range collect with one block scan, bitonic sort of 1024
// (key<<32|idx) items, scatter at position = slot.
__global__ __launch_bounds__(1024) void k_select(const float* __restrict__ pred,
    const u32* __restrict__ keys_g, const u32* __restrict__ cls_g,
    float* __restrict__ selBox, float* __restrict__ selOb, float* __restrict__ selArea,
    float* __restrict__ selScore, float* __restrict__ selCls, u32* __restrict__ selValid) {
  extern __shared__ char smem[];
  u32* keys = (u32*)smem;                 // [25200]  100800 B
  u32* hist = (u32*)(smem + 100800);      // [256]    -> 101824
  u32* wsum = (u32*)(smem + 101824);      // [32]     -> 101952
  u32* bc   = (u32*)(smem + 101952);      // [8]      -> 101984
  u64* items= (u64*)(smem + 101984);      // [1024]   -> 110176

  const int b = blockIdx.x;
  const int t = threadIdx.x;
  const int lane = t & 63;
  const int wv = t >> 6;

  {
    uint4* k4 = (uint4*)keys;
    const uint4* g4 = (const uint4*)(keys_g + b * N_ROWS);
    for (int i = t; i < N_ROWS / 4; i += 1024) k4[i] = g4[i];
  }
  items[t] = 0xFFFFFFFF00000000ull | (u32)t;   // distinct pads, sort last
  if (t == 0) { bc[0] = 0u; bc[1] = 999u; }
  __syncthreads();

  // ---- radix-select T = key of rank 999 ----
  for (int lev = 3; lev >= 0; --lev) {
    if (t < 256) hist[t] = 0u;
    __syncthreads();
    const u32 prefix = bc[0];
    const u32 target = bc[1];
    const u32 maskhi = (lev == 3) ? 0u : (0xFFFFFFFFu << ((lev + 1) * 8));
    const int sh = lev * 8;
    for (int base = 0; base < N_ROWS; base += 1024) {
      int i = base + t;
      bool pr = false; u32 bk = 0;
      if (i < N_ROWS) { u32 k = keys[i]; pr = ((k & maskhi) == prefix); bk = (k >> sh) & 255u; }
      if (lev == 3) {
        u64 act = __ballot(pr);            // wave-aggregated: few hot buckets
        while (act) {
          int ldr = __ffsll((unsigned long long)act) - 1;
          u32 lb = __shfl(bk, ldr);
          u64 same = __ballot(pr && (bk == lb));
          if (lane == ldr) atomicAdd(&hist[lb], (u32)__popcll(same));
          act &= ~same;
        }
      } else {
        if (pr) atomicAdd(&hist[bk], 1u);  // mantissa levels: spread bins
      }
    }
    __syncthreads();
    if (t < 64) {                          // parallel digit scan on wave 0
      u32 c0 = hist[t*4], c1 = hist[t*4+1], c2 = hist[t*4+2], c3 = hist[t*4+3];
      u32 s4 = c0 + c1 + c2 + c3;
      u32 inc = s4;
      #pragma unroll
      for (int d = 1; d < 64; d <<= 1) { u32 o = __shfl_up(inc, d); if (lane >= d) inc += o; }
      u32 excl = inc - s4;
      u64 mb = __ballot(inc > target);
      int L = __ffsll((unsigned long long)mb) - 1;
      if (t == L) {
        u32 cum = excl; u32 d = (u32)t * 4u;
        if (cum + c0 <= target) { cum += c0; d++;
          if (cum + c1 <= target) { cum += c1; d++;
            if (cum + c2 <= target) { cum += c2; d++; } } }
        bc[0] = prefix | (d << sh);
        bc[1] = target - cum;
      }
    }
    __syncthreads();
  }
  const u32 T = bc[0];

  // ---- collect: contiguous per-thread ranges preserve index order ----
  const int RPT = 25;                      // 1024*25 >= 25200
  const int i0 = t * RPT;
  u32 c0 = 0, c1 = 0;
  for (int r = 0; r < RPT; ++r) {
    int i = i0 + r;
    if (i < N_ROWS) { u32 k = keys[i]; c0 += (k < T); c1 += (k == T); }
  }
  u32 packed = (c0 << 16) | c1;
  u32 inc = packed;
  #pragma unroll
  for (int d = 1; d < 64; d <<= 1) { u32 o = __shfl_up(inc, d); if (lane >= d) inc += o; }
  if (lane == 63) wsum[wv] = inc;
  __syncthreads();
  if (t < 16) {
    u32 v = wsum[t]; u32 iv = v;
    #pragma unroll
    for (int d = 1; d < 16; d <<= 1) { u32 o = __shfl_up(iv, d); if (lane >= d) iv += o; }
    wsum[t] = iv - v;
    if (t == 15) bc[2] = iv;
  }
  __syncthreads();
  u32 excl = inc - packed + wsum[wv];
  u32 total0 = bc[2] >> 16;
  u32 p0 = excl >> 16;
  u32 p1 = total0 + (excl & 0xFFFFu);
  for (int r = 0; r < RPT; ++r) {
    int i = i0 + r;
    if (i < N_ROWS) {
      u32 k = keys[i];
      if (k < T)       { items[p0] = ((u64)k << 32) | (u32)i; p0++; }
      else if (k == T) { if (p1 < (u32)MAX_NMS) items[p1] = ((u64)k << 32) | (u32)i; p1++; }
    }
  }
  __syncthreads();

  // ---- bitonic sort 1024 u64 ascending: (key, idx) ----
  for (int k = 2; k <= 1024; k <<= 1) {
    for (int j = k >> 1; j > 0; j >>= 1) {
      __syncthreads();
      int ixj = t ^ j;
      if (ixj > t) {
        u64 a = items[t], bb = items[ixj];
        bool sw = ((t & k) == 0) ? (a > bb) : (a < bb);
        if (sw) { items[t] = bb; items[ixj] = a; }
      }
    }
  }
  __syncthreads();

  // ---- gather + scatter: slot t holds rank-t item ----
  if (t < MAX_NMS) {
    u64 it = items[t];
    u32 key = (u32)(it >> 32);
    u32 row = (u32)(it & 0xFFFFFFFFu);
    u32 o = ~key;
    u32 sb = (o & 0x80000000u) ? (o ^ 0x80000000u) : ~o;   // invert score_key
    float score = __uint_as_float(sb);
    u32 valid = (key != KEY_INVALID) ? 1u : 0u;
    const float* p = pred + ((size_t)b * N_ROWS + row) * N_FEAT;
    float x = p[0], y = p[1], w = p[2], h = p[3];
    float x1 = x - w * 0.5f, y1 = y - h * 0.5f;
    float x2 = x + w * 0.5f, y2 = y + h * 0.5f;
    float cf = (float)cls_g[b * N_ROWS + row];
    float offv = cf * 4096.0f;
    float o0 = x1 + offv, o1 = y1 + offv, o2 = x2 + offv, o3 = y2 + offv;
    float area = (o2 - o0) * (o3 - o1);        // area from OFFSET boxes (ref)
    int idx = b * 1024 + t;
    selBox[idx * 4 + 0] = x1; selBox[idx * 4 + 1] = y1;
    selBox[idx * 4 + 2] = x2; selBox[idx * 4 + 3] = y2;
    selOb [idx * 4 + 0] = o0; selOb [idx * 4 + 1] = o1;
    selOb [idx * 4 + 2] = o2; selOb [idx * 4 + 3] = o3;
    selArea[idx] = area;
    selScore[idx] = score;
    selCls[idx] = cf;
    selValid[idx] = valid;
  }
}

// ---- Stage C: 1000x1000 IoU>thr bitmask, lanes on the j-axis. ----
// Grid (32 chunks of 32 rows, 16 batches). Per (row, word): one ds_read_b128
// + one ds_read_b32 per lane (conflict-free), word built by __ballot.
__global__ __launch_bounds__(256) void k_mask(const float* __restrict__ selOb,
                                              const float* __restrict__ selArea,
                                              u64* __restrict__ gmask) {
  __shared__ float shob[1024 * 4];
  __shared__ float sharea[1024];
  const int chunk = blockIdx.x;
  const int b = blockIdx.y;
  const int t = threadIdx.x;
  const int lane = t & 63;
  const int wv = t >> 6;
  {
    float4* so4 = (float4*)shob;
    const float4* go4 = (const float4*)(selOb + (size_t)b * 4096);
    for (int i = t; i < 1024; i += 256) so4[i] = go4[i];
    float4* sa4 = (float4*)sharea;
    const float4* ga4 = (const float4*)(selArea + (size_t)b * 1024);
    if (t < 256) sa4[t] = ga4[t];
  }
  __syncthreads();
  const float4* job = (const float4*)shob;
  for (int k = 0; k < 8; ++k) {
    int i = chunk * 32 + wv * 8 + k;       // wave-uniform
    if (i >= MAX_NMS) break;
    float a0 = shob[i*4+0], a1 = shob[i*4+1], a2 = shob[i*4+2], a3 = shob[i*4+3];
    float aa = sharea[i];
    #pragma unroll 4
    for (int w = 0; w < 16; ++w) {
      int j = w * 64 + lane;
      float4 bb = job[j];                  // conflict-free b128
      float aj = sharea[j];
      float lt0 = fmaxf(a0, bb.x);
      float lt1 = fmaxf(a1, bb.y);
      float rb0 = fminf(a2, bb.z);
      float rb1 = fminf(a3, bb.w);
      float ww = fmaxf(rb0 - lt0, 0.0f);
      float hh = fmaxf(rb1 - lt1, 0.0f);
      float inter = ww * hh;
      float den = aa + aj - inter + 1e-7f; // ((aa+aj)-inter)+eps, like ref
      float iou = inter / den;             // IEEE f32 div, like ref
      u64 bits = __ballot(iou > 0.45f);    // bit l <-> j = w*64+l
      if (lane == 0) gmask[((size_t)b * MAX_NMS + i) * 16 + w] = bits;
    }
  }
}

// ---- Stage D: greedy scan + output. One block per batch; wave 0 scans. ----
__global__ __launch_bounds__(256) void k_scan(const u64* __restrict__ gmask,
                                              const u32* __restrict__ selValid,
                                              const float* __restrict__ selBox,
                                              const float* __restrict__ selScore,
                                              const float* __restrict__ selCls,
                                              float* __restrict__ out) {
  extern __shared__ char smem[];
  u64* m = (u64*)smem;                         // [16000]  128000 B
  unsigned char* val = (unsigned char*)(smem + 128000);  // [1000]
  int* order = (int*)(smem + 129000);          // [300]
  u32* pcnt = (u32*)(smem + 130200);
  const int b = blockIdx.x;
  const int t = threadIdx.x;
  const u64* gm = gmask + (size_t)b * (MAX_NMS * 16);
  for (int i = t; i < MAX_NMS * 16; i += 256) m[i] = gm[i];
  for (int i = t; i < MAX_NMS; i += 256) val[i] = (unsigned char)selValid[b * 1024 + i];
  __syncthreads();

  if (t < 64) {
    u64 remv = 0; int cnt = 0;
    for (int i = 0; i < MAX_NMS && cnt < MAX_DET; ++i) {
      int w = i >> 6;
      u64 rw = __shfl(remv, w);
      bool sup = (rw >> (i & 63)) & 1ull;
      bool ki = (val[i] != 0) && !sup;
      if (ki) {
        if (t < 16) remv |= m[i * 16 + t];
        if (t == 0) order[cnt] = i;
        ++cnt;
      }
    }
    if (t == 0) *pcnt = (u32)cnt;
  }
  __syncthreads();
  int cnt = (int)*pcnt;
  for (int s = t; s < MAX_DET; s += 256) {
    float o0=0,o1=0,o2=0,o3=0,o4=0,o5=0;
    if (s < cnt) {
      int i = order[s];
      int idx = b * 1024 + i;
      o0 = selBox[idx*4+0]; o1 = selBox[idx*4+1];
      o2 = selBox[idx*4+2]; o3 = selBox[idx*4+3];
      o4 = selScore[idx];   o5 = selCls[idx];
    }
    float* op = out + ((size_t)b * MAX_DET + s) * 6;
    op[0]=o0; op[1]=o1; op[2]=o2; op[3]=o3; op[4]=o4; op[5]=o5;
  }
}

extern "C" void kernel_launch(void* const* d_in, const int* in_sizes, int n_in,
                              void* d_out, int out_size, void* d_ws, size_t ws_size,
                              hipStream_t stream) {
  const float* pred = (const float*)d_in[0];
  float* out = (float*)d_out;
  char* ws = (char*)d_ws;
  u32* keys     = (u32*)(ws + WS_KEYS);
  u32* cls      = (u32*)(ws + WS_CLS);
  float* selBox = (float*)(ws + WS_SELBOX);
  float* selOb  = (float*)(ws + WS_SELOB);
  float* selArea= (float*)(ws + WS_SELAREA);
  float* selScore=(float*)(ws + WS_SELSC);
  float* selCls = (float*)(ws + WS_SELCLS);
  u32* selValid = (u32*)(ws + WS_SELVAL);
  u64* gmask    = (u64*)(ws + WS_GMASK);

  k_score<<<KS_GRID, 256, 0, stream>>>(pred, keys, cls);
  k_select<<<N_BATCH, 1024, 110176, stream>>>(pred, keys, cls, selBox, selOb, selArea,
                                              selScore, selCls, selValid);
  k_mask<<<dim3(32, N_BATCH), 256, 0, stream>>>(selOb, selArea, gmask);
  k_scan<<<N_BATCH, 256, 130208, stream>>>(gmask, selValid, selBox, selScore, selCls, out);
}

// Round 5
// 148.706 us; speedup vs baseline: 1.8069x; 1.1154x over previous
//
#include <hip/hip_runtime.h>
#include <cstdint>

typedef unsigned int u32;
typedef unsigned long long u64;

#define N_BATCH 16
#define N_ROWS  25200
#define N_FEAT  85
#define N_CLS   80
#define MAX_NMS 1000
#define MAX_DET 300
#define KEY_INVALID 0xFF800000u   // key(-inf)

// ---- workspace layout (bytes) ----
#define WS_KEYS    0u                          // 16*25200*4 = 1,612,800
#define WS_CLS     1612800u                    // 16*25200*4
#define WS_SELBOX  3225600u                    // 16*1024*4*4 = 262,144
#define WS_SELOB   3487744u                    // 262,144
#define WS_SELAREA 3749888u                    // 16*1024*4 = 65,536
#define WS_SELSC   3815424u                    // 65,536
#define WS_SELCLS  3880960u                    // 65,536
#define WS_SELVAL  3946496u                    // 65,536
#define WS_GMASK   4012032u                    // 16*1000*16*8 = 2,048,000

__device__ __forceinline__ u32 score_key(float s) {
  u32 u = __float_as_uint(s);
  u32 o = (u & 0x80000000u) ? ~u : (u | 0x80000000u);
  return ~o;   // ascending key == descending score
}

__device__ __forceinline__ u64 shfl_xor_u64(u64 x, int m) {
  u32 lo = (u32)x, hi = (u32)(x >> 32);
  lo = __shfl_xor(lo, m); hi = __shfl_xor(hi, m);
  return ((u64)hi << 32) | lo;
}
__device__ __forceinline__ u64 shfl_u64(u64 x, int src) {
  u32 lo = (u32)x, hi = (u32)(x >> 32);
  lo = __shfl(lo, src); hi = __shfl(hi, src);
  return ((u64)hi << 32) | lo;
}

// ---- Stage A: per-row score/class, async-pipelined LDS staging. ----
// (unchanged from round 3 — known-good)
#define KS_CHUNK  32
#define KS_CBYTES (KS_CHUNK * N_FEAT * 4)     // 10880
#define KS_GRID   1792                        // 7 blocks/CU * 256 CU
#define KS_NCHUNK ((N_BATCH * N_ROWS) / KS_CHUNK)   // 12600

__device__ __forceinline__ void ks_stage(const float* pred, int c, u32* lbuf,
                                         int wv, int lane) {
  const char* g = (const char*)pred + (size_t)c * KS_CBYTES;
  const int u0 = wv * 170;
  u32* l0 = lbuf + u0 * 4;
  __builtin_amdgcn_global_load_lds(
      (const __attribute__((address_space(1))) u32*)(g + (size_t)(u0 + lane) * 16),
      (__attribute__((address_space(3))) u32*)(l0), 16, 0, 0);
  __builtin_amdgcn_global_load_lds(
      (const __attribute__((address_space(1))) u32*)(g + (size_t)(u0 + 64 + lane) * 16),
      (__attribute__((address_space(3))) u32*)(l0 + 256), 16, 0, 0);
  if (lane < 42)
    __builtin_amdgcn_global_load_lds(
        (const __attribute__((address_space(1))) u32*)(g + (size_t)(u0 + 128 + lane) * 16),
        (__attribute__((address_space(3))) u32*)(l0 + 512), 16, 0, 0);
}

__global__ __launch_bounds__(256) void k_score(const float* __restrict__ pred,
                                               u32* __restrict__ keys,
                                               u32* __restrict__ clsArr) {
  __shared__ __align__(16) u32 sbuf[2][KS_CBYTES / 4];
  const int t = threadIdx.x;
  const int lane = t & 63;
  const int wv = t >> 6;
  const int row = (lane >> 3) + wv * 8;     // 0..31 within chunk
  const int sub = lane & 7;                 // class slice [10*sub, 10*sub+10)

  ks_stage(pred, blockIdx.x, sbuf[0], wv, lane);
  ks_stage(pred, blockIdx.x + KS_GRID, sbuf[1], wv, lane);

  int it = 0;
  for (int c = blockIdx.x; c < KS_NCHUNK; c += KS_GRID, ++it) {
    const bool has_next = (c + KS_GRID < KS_NCHUNK);
    if (it == 0)        asm volatile("s_waitcnt vmcnt(3)" ::: "memory");
    else if (has_next)  asm volatile("s_waitcnt vmcnt(5)" ::: "memory");
    else                asm volatile("s_waitcnt vmcnt(2)" ::: "memory");
    __builtin_amdgcn_sched_barrier(0);
    __builtin_amdgcn_s_barrier();

    const u32* rp = sbuf[it & 1] + row * N_FEAT;
    float obj = __uint_as_float(rp[4]);
    float best = -__builtin_inff();
    int bi = 0;
    const u32* cp = rp + 5 + sub * 10;
    #pragma unroll
    for (int k = 0; k < 10; ++k) {
      float cc = __uint_as_float(cp[k]) * obj;         // exact reference product
      if (cc > best) { best = cc; bi = sub * 10 + k; } // strict > = first occ.
    }
    #pragma unroll
    for (int d = 1; d <= 4; d <<= 1) {
      float ob = __shfl_xor(best, d);
      int oj = __shfl_xor(bi, d);
      if (ob > best || (ob == best && oj < bi)) { best = ob; bi = oj; }
    }
    if (sub == 0) {
      bool valid = (obj > 0.3f) && (best > 0.3f);
      float s = valid ? best : -__builtin_inff();
      int gr = c * KS_CHUNK + row;
      keys[gr] = score_key(s);
      clsArr[gr] = (u32)bi;
    }
    __builtin_amdgcn_s_barrier();
    if (c + 2 * KS_GRID < KS_NCHUNK)
      ks_stage(pred, c + 2 * KS_GRID, sbuf[it & 1], wv, lane);
  }
}

// ---- Stage B: per-batch exact top-1000 (desc score, asc index ties). ----
// Radix-select T, contiguous-range collect, then REGISTER bitonic sort:
// j<64 stages via shfl_xor (no barrier), j>=64 stages via LDS (10 stages).
__global__ __launch_bounds__(1024) void k_select(const float* __restrict__ pred,
    const u32* __restrict__ keys_g, const u32* __restrict__ cls_g,
    float* __restrict__ selBox, float* __restrict__ selOb, float* __restrict__ selArea,
    float* __restrict__ selScore, float* __restrict__ selCls, u32* __restrict__ selValid) {
  extern __shared__ char smem[];
  u32* keys = (u32*)smem;                 // [25200]  100800 B
  u32* hist = (u32*)(smem + 100800);      // [256]    -> 101824
  u32* wsum = (u32*)(smem + 101824);      // [32]     -> 101952
  u32* bc   = (u32*)(smem + 101952);      // [8]      -> 101984
  u64* items= (u64*)(smem + 101984);      // [1024]   -> 110176

  const int b = blockIdx.x;
  const int t = threadIdx.x;
  const int lane = t & 63;
  const int wv = t >> 6;

  {
    uint4* k4 = (uint4*)keys;
    const uint4* g4 = (const uint4*)(keys_g + b * N_ROWS);
    for (int i = t; i < N_ROWS / 4; i += 1024) k4[i] = g4[i];
  }
  items[t] = 0xFFFFFFFF00000000ull | (u32)t;   // distinct pads, sort last
  if (t == 0) { bc[0] = 0u; bc[1] = 999u; }
  __syncthreads();

  // ---- radix-select T = key of rank 999 ----
  for (int lev = 3; lev >= 0; --lev) {
    if (t < 256) hist[t] = 0u;
    __syncthreads();
    const u32 prefix = bc[0];
    const u32 target = bc[1];
    const u32 maskhi = (lev == 3) ? 0u : (0xFFFFFFFFu << ((lev + 1) * 8));
    const int sh = lev * 8;
    for (int base = 0; base < N_ROWS; base += 1024) {
      int i = base + t;
      bool pr = false; u32 bk = 0;
      if (i < N_ROWS) { u32 k = keys[i]; pr = ((k & maskhi) == prefix); bk = (k >> sh) & 255u; }
      if (lev == 3) {
        u64 act = __ballot(pr);            // wave-aggregated: few hot buckets
        while (act) {
          int ldr = __ffsll((unsigned long long)act) - 1;
          u32 lb = __shfl(bk, ldr);
          u64 same = __ballot(pr && (bk == lb));
          if (lane == ldr) atomicAdd(&hist[lb], (u32)__popcll(same));
          act &= ~same;
        }
      } else {
        if (pr) atomicAdd(&hist[bk], 1u);  // mantissa levels: spread bins
      }
    }
    __syncthreads();
    if (t < 64) {                          // parallel digit scan on wave 0
      u32 c0 = hist[t*4], c1 = hist[t*4+1], c2 = hist[t*4+2], c3 = hist[t*4+3];
      u32 s4 = c0 + c1 + c2 + c3;
      u32 inc = s4;
      #pragma unroll
      for (int d = 1; d < 64; d <<= 1) { u32 o = __shfl_up(inc, d); if (lane >= d) inc += o; }
      u32 excl = inc - s4;
      u64 mb = __ballot(inc > target);
      int L = __ffsll((unsigned long long)mb) - 1;
      if (t == L) {
        u32 cum = excl; u32 d = (u32)t * 4u;
        if (cum + c0 <= target) { cum += c0; d++;
          if (cum + c1 <= target) { cum += c1; d++;
            if (cum + c2 <= target) { cum += c2; d++; } } }
        bc[0] = prefix | (d << sh);
        bc[1] = target - cum;
      }
    }
    __syncthreads();
  }
  const u32 T = bc[0];

  // ---- collect: contiguous per-thread ranges preserve index order ----
  const int RPT = 25;                      // 1024*25 >= 25200
  const int i0 = t * RPT;
  u32 c0 = 0, c1 = 0;
  for (int r = 0; r < RPT; ++r) {
    int i = i0 + r;
    if (i < N_ROWS) { u32 k = keys[i]; c0 += (k < T); c1 += (k == T); }
  }
  u32 packed = (c0 << 16) | c1;
  u32 inc = packed;
  #pragma unroll
  for (int d = 1; d < 64; d <<= 1) { u32 o = __shfl_up(inc, d); if (lane >= d) inc += o; }
  if (lane == 63) wsum[wv] = inc;
  __syncthreads();
  if (t < 16) {
    u32 v = wsum[t]; u32 iv = v;
    #pragma unroll
    for (int d = 1; d < 16; d <<= 1) { u32 o = __shfl_up(iv, d); if (lane >= d) iv += o; }
    wsum[t] = iv - v;
    if (t == 15) bc[2] = iv;
  }
  __syncthreads();
  u32 excl = inc - packed + wsum[wv];
  u32 total0 = bc[2] >> 16;
  u32 p0 = excl >> 16;
  u32 p1 = total0 + (excl & 0xFFFFu);
  for (int r = 0; r < RPT; ++r) {
    int i = i0 + r;
    if (i < N_ROWS) {
      u32 k = keys[i];
      if (k < T)       { items[p0] = ((u64)k << 32) | (u32)i; p0++; }
      else if (k == T) { if (p1 < (u32)MAX_NMS) items[p1] = ((u64)k << 32) | (u32)i; p1++; }
    }
  }
  __syncthreads();

  // ---- hybrid bitonic sort, ascending (key, idx); value in register v ----
  u64 v = items[t];
  // intra-wave presort: k = 2..64, all stages via shfl_xor (no barriers)
  #pragma unroll
  for (int k = 2; k <= 64; k <<= 1) {
    for (int j = k >> 1; j > 0; j >>= 1) {
      u64 p = shfl_xor_u64(v, j);
      bool keepmin = (((t & k) == 0) == ((t & j) == 0));
      v = (keepmin == (v < p)) ? v : p;
    }
  }
  // k = 128..1024: cross-wave stages (j>=64) via LDS, tail via shfl
  for (int k = 128; k <= 1024; k <<= 1) {
    for (int j = k >> 1; j >= 64; j >>= 1) {
      items[t] = v;
      __syncthreads();
      u64 p = items[t ^ j];
      bool keepmin = (((t & k) == 0) == ((t & j) == 0));
      v = (keepmin == (v < p)) ? v : p;
      __syncthreads();
    }
    #pragma unroll
    for (int j = 32; j > 0; j >>= 1) {
      u64 p = shfl_xor_u64(v, j);
      bool keepmin = (((t & k) == 0) == ((t & j) == 0));
      v = (keepmin == (v < p)) ? v : p;
    }
  }
  // v now holds the rank-t item; no LDS round-trip needed for gather.

  // ---- gather + scatter: slot t holds rank-t item ----
  if (t < MAX_NMS) {
    u64 it = v;
    u32 key = (u32)(it >> 32);
    u32 row = (u32)(it & 0xFFFFFFFFu);
    u32 o = ~key;
    u32 sb = (o & 0x80000000u) ? (o ^ 0x80000000u) : ~o;   // invert score_key
    float score = __uint_as_float(sb);
    u32 valid = (key != KEY_INVALID) ? 1u : 0u;
    const float* p = pred + ((size_t)b * N_ROWS + row) * N_FEAT;
    float x = p[0], y = p[1], w = p[2], h = p[3];
    float x1 = x - w * 0.5f, y1 = y - h * 0.5f;
    float x2 = x + w * 0.5f, y2 = y + h * 0.5f;
    float cf = (float)cls_g[b * N_ROWS + row];
    float offv = cf * 4096.0f;
    float o0 = x1 + offv, o1 = y1 + offv, o2 = x2 + offv, o3 = y2 + offv;
    float area = (o2 - o0) * (o3 - o1);        // area from OFFSET boxes (ref)
    int idx = b * 1024 + t;
    selBox[idx * 4 + 0] = x1; selBox[idx * 4 + 1] = y1;
    selBox[idx * 4 + 2] = x2; selBox[idx * 4 + 3] = y2;
    selOb [idx * 4 + 0] = o0; selOb [idx * 4 + 1] = o1;
    selOb [idx * 4 + 2] = o2; selOb [idx * 4 + 3] = o3;
    selArea[idx] = area;
    selScore[idx] = score;
    selCls[idx] = cf;
    selValid[idx] = valid;
  }
}

// ---- Stage C: 1000x1000 IoU>thr bitmask, lanes on the j-axis. ----
// (unchanged from round 3)
__global__ __launch_bounds__(256) void k_mask(const float* __restrict__ selOb,
                                              const float* __restrict__ selArea,
                                              u64* __restrict__ gmask) {
  __shared__ float shob[1024 * 4];
  __shared__ float sharea[1024];
  const int chunk = blockIdx.x;
  const int b = blockIdx.y;
  const int t = threadIdx.x;
  const int lane = t & 63;
  const int wv = t >> 6;
  {
    float4* so4 = (float4*)shob;
    const float4* go4 = (const float4*)(selOb + (size_t)b * 4096);
    for (int i = t; i < 1024; i += 256) so4[i] = go4[i];
    float4* sa4 = (float4*)sharea;
    const float4* ga4 = (const float4*)(selArea + (size_t)b * 1024);
    if (t < 256) sa4[t] = ga4[t];
  }
  __syncthreads();
  const float4* job = (const float4*)shob;
  for (int k = 0; k < 8; ++k) {
    int i = chunk * 32 + wv * 8 + k;       // wave-uniform
    if (i >= MAX_NMS) break;
    float a0 = shob[i*4+0], a1 = shob[i*4+1], a2 = shob[i*4+2], a3 = shob[i*4+3];
    float aa = sharea[i];
    #pragma unroll 4
    for (int w = 0; w < 16; ++w) {
      int j = w * 64 + lane;
      float4 bb = job[j];                  // conflict-free b128
      float aj = sharea[j];
      float lt0 = fmaxf(a0, bb.x);
      float lt1 = fmaxf(a1, bb.y);
      float rb0 = fminf(a2, bb.z);
      float rb1 = fminf(a3, bb.w);
      float ww = fmaxf(rb0 - lt0, 0.0f);
      float hh = fmaxf(rb1 - lt1, 0.0f);
      float inter = ww * hh;
      float den = aa + aj - inter + 1e-7f; // ((aa+aj)-inter)+eps, like ref
      float iou = inter / den;             // IEEE f32 div, like ref
      u64 bits = __ballot(iou > 0.45f);    // bit l <-> j = w*64+l
      if (lane == 0) gmask[((size_t)b * MAX_NMS + i) * 16 + w] = bits;
    }
  }
}

// ---- Stage D: ffs-skip greedy scan + output. One block per batch. ----
// Lanes 0-15 hold the 1000-bit alive vector (valid & ~suppressed) in
// registers. Each iteration picks the LOWEST alive index (== serial scan
// order, since suppression only clears bits), records it, ANDs out its mask
// row. Iterations = #keeps (<=300) instead of 1000.
__global__ __launch_bounds__(256) void k_scan(const u64* __restrict__ gmask,
                                              const u32* __restrict__ selValid,
                                              const float* __restrict__ selBox,
                                              const float* __restrict__ selScore,
                                              const float* __restrict__ selCls,
                                              float* __restrict__ out) {
  extern __shared__ char smem[];
  u64* m = (u64*)smem;                       // [16000] 128000 B
  u64* aw = (u64*)(smem + 128000);           // [16]    -> 128128
  int* order = (int*)(smem + 128128);        // [300]   -> 129328
  u32* pcnt = (u32*)(smem + 129328);         // -> 129332
  const int b = blockIdx.x;
  const int t = threadIdx.x;
  {
    uint4* m4 = (uint4*)m;
    const uint4* g4 = (const uint4*)(gmask + (size_t)b * (MAX_NMS * 16));
    for (int i = t; i < MAX_NMS * 4; i += 256) m4[i] = g4[i];   // 16000 u64 = 4000 uint4
  }
  // alive words: word w covers slots 64w..64w+63; slots >= MAX_NMS forced dead
  for (int s = t; s < 1024; s += 256) {
    u32 vv = (s < MAX_NMS) ? selValid[b * 1024 + s] : 0u;
    u64 bal = __ballot(vv != 0u);
    if ((s & 63) == 0) aw[s >> 6] = bal;
  }
  __syncthreads();

  if (t < 64) {
    u64 A = (t < 16) ? aw[t] : 0ull;
    int cnt = 0;
    while (cnt < MAX_DET) {
      u64 nz = __ballot(A != 0ull);
      if (nz == 0ull) break;
      int w0 = __ffsll((unsigned long long)nz) - 1;
      u64 Aw = shfl_u64(A, w0);
      int bit = __ffsll((unsigned long long)Aw) - 1;
      int i = (w0 << 6) + bit;
      if (t == 0) order[cnt] = i;
      ++cnt;
      if (t < 16) A &= ~m[i * 16 + t];       // suppress row i (self-iou=1 clears bit i)
      if (t == w0) A &= ~(1ull << bit);      // insurance vs degenerate self-row
    }
    if (t == 0) *pcnt = (u32)cnt;
  }
  __syncthreads();
  int cnt = (int)*pcnt;
  for (int s = t; s < MAX_DET; s += 256) {
    float o0=0,o1=0,o2=0,o3=0,o4=0,o5=0;
    if (s < cnt) {
      int i = order[s];
      int idx = b * 1024 + i;
      o0 = selBox[idx*4+0]; o1 = selBox[idx*4+1];
      o2 = selBox[idx*4+2]; o3 = selBox[idx*4+3];
      o4 = selScore[idx];   o5 = selCls[idx];
    }
    float* op = out + ((size_t)b * MAX_DET + s) * 6;
    op[0]=o0; op[1]=o1; op[2]=o2; op[3]=o3; op[4]=o4; op[5]=o5;
  }
}

extern "C" void kernel_launch(void* const* d_in, const int* in_sizes, int n_in,
                              void* d_out, int out_size, void* d_ws, size_t ws_size,
                              hipStream_t stream) {
  const float* pred = (const float*)d_in[0];
  float* out = (float*)d_out;
  char* ws = (char*)d_ws;
  u32* keys     = (u32*)(ws + WS_KEYS);
  u32* cls      = (u32*)(ws + WS_CLS);
  float* selBox = (float*)(ws + WS_SELBOX);
  float* selOb  = (float*)(ws + WS_SELOB);
  float* selArea= (float*)(ws + WS_SELAREA);
  float* selScore=(float*)(ws + WS_SELSC);
  float* selCls = (float*)(ws + WS_SELCLS);
  u32* selValid = (u32*)(ws + WS_SELVAL);
  u64* gmask    = (u64*)(ws + WS_GMASK);

  k_score<<<KS_GRID, 256, 0, stream>>>(pred, keys, cls);
  k_select<<<N_BATCH, 1024, 110176, stream>>>(pred, keys, cls, selBox, selOb, selArea,
                                              selScore, selCls, selValid);
  k_mask<<<dim3(32, N_BATCH), 256, 0, stream>>>(selOb, selArea, gmask);
  k_scan<<<N_BATCH, 256, 129344, stream>>>(gmask, selValid, selBox, selScore, selCls, out);
}